// Round 1
// baseline (1254.994 us; speedup 1.0000x reference)
//
#include <hip/hip_runtime.h>

// GNNML3 forward: 4x SpectConv(K=5) + relu, sum/max pool per graph, BN + FC + log_softmax.
// Key identity: (S_k x) W_k == S_k (x W_k) -> aggregate at input width, then dense GEMM.
// CSR-by-dst built per call (histogram + scan + scatter) -> register accumulation, no float atomics.

#define Nn   50000
#define Ne   1600000
#define Gg   128
#define NEk  5
#define NINf 16
#define Hh   64
#define NCLSo 6

// ---------------- prep kernels ----------------

__global__ void k_pad_x(const float* __restrict__ x, float* __restrict__ h0) {
    int i = blockIdx.x * 256 + threadIdx.x;           // over Nn*64
    if (i >= Nn * 64) return;
    int n = i >> 6, f = i & 63;
    h0[i] = (f < NINf) ? x[n * NINf + f] : 0.f;
}

__global__ void k_pad_w1(const float* __restrict__ W1, float* __restrict__ W1p) {
    int i = blockIdx.x * 256 + threadIdx.x;           // over 5*64*64
    if (i >= NEk * 64 * 64) return;
    int h = i & 63, f = (i >> 6) & 63, k = i >> 12;
    W1p[i] = (f < NINf) ? W1[(k * NINf + f) * 64 + h] : 0.f;
}

__global__ void k_hist(const int* __restrict__ ei, int* __restrict__ deg) {
    int e = blockIdx.x * 256 + threadIdx.x;
    if (e >= Ne) return;
    atomicAdd(&deg[ei[Ne + e]], 1);                   // dst = ei[1][e]
}

// single-block exclusive scan over deg[0..Nn) -> rowstart[0..Nn], cursor copy
__global__ void k_scan(const int* __restrict__ deg, int* __restrict__ rowstart,
                       int* __restrict__ cursor) {
    __shared__ int lds[1024];
    int t = threadIdx.x;
    int carry = 0;
    for (int base = 0; base <= Nn; base += 1024) {
        int i = base + t;
        int v = (i < Nn) ? deg[i] : 0;
        lds[t] = v;
        __syncthreads();
        for (int off = 1; off < 1024; off <<= 1) {
            int u = (t >= off) ? lds[t - off] : 0;
            __syncthreads();
            lds[t] += u;
            __syncthreads();
        }
        int incl = lds[t];
        int excl = incl - v + carry;
        if (i <= Nn) { rowstart[i] = excl; cursor[i] = excl; }
        carry += lds[1023];
        __syncthreads();
    }
}

__global__ void k_scatter(const int* __restrict__ ei, const float* __restrict__ eattr,
                          int* __restrict__ cursor, int* __restrict__ srcs,
                          float* __restrict__ attr) {
    int e = blockIdx.x * 256 + threadIdx.x;
    if (e >= Ne) return;
    int d = ei[Ne + e];
    int s = ei[e];
    int pos = atomicAdd(&cursor[d], 1);
    srcs[pos] = s;
    float a0 = eattr[e * 5 + 0], a1 = eattr[e * 5 + 1], a2 = eattr[e * 5 + 2];
    float a3 = eattr[e * 5 + 3], a4 = eattr[e * 5 + 4];
    attr[pos * 5 + 0] = a0; attr[pos * 5 + 1] = a1; attr[pos * 5 + 2] = a2;
    attr[pos * 5 + 3] = a3; attr[pos * 5 + 4] = a4;
}

__global__ void k_ranges(const int* __restrict__ batch, int* __restrict__ sg,
                         int* __restrict__ eg) {
    int n = blockIdx.x * 256 + threadIdx.x;
    if (n >= Nn) return;
    int g = batch[n];
    atomicMin(&sg[g], n);
    atomicMax(&eg[g], n + 1);
}

// ---------------- per-layer kernels ----------------

// one wave per node; lane = feature f (0..63); 5 register accumulators (spectral supports)
__global__ __launch_bounds__(256) void k_aggregate(
    const float* __restrict__ hin, const int* __restrict__ rowstart,
    const int* __restrict__ srcs, const float* __restrict__ attr,
    float* __restrict__ agg) {
    int lane = threadIdx.x & 63;
    int node = __builtin_amdgcn_readfirstlane((int)(blockIdx.x * 4 + (threadIdx.x >> 6)));
    int beg = rowstart[node];
    int end = rowstart[node + 1];
    float acc0 = 0.f, acc1 = 0.f, acc2 = 0.f, acc3 = 0.f, acc4 = 0.f;
    int e = beg;
    for (; e + 2 <= end; e += 2) {
        int s0 = srcs[e], s1 = srcs[e + 1];
        float x0 = hin[(size_t)s0 * 64 + lane];
        float x1 = hin[(size_t)s1 * 64 + lane];
        float c0 = attr[e * 5 + 0], c1 = attr[e * 5 + 1], c2 = attr[e * 5 + 2];
        float c3 = attr[e * 5 + 3], c4 = attr[e * 5 + 4];
        float d0 = attr[e * 5 + 5], d1 = attr[e * 5 + 6], d2 = attr[e * 5 + 7];
        float d3 = attr[e * 5 + 8], d4 = attr[e * 5 + 9];
        acc0 = fmaf(c0, x0, acc0); acc1 = fmaf(c1, x0, acc1); acc2 = fmaf(c2, x0, acc2);
        acc3 = fmaf(c3, x0, acc3); acc4 = fmaf(c4, x0, acc4);
        acc0 = fmaf(d0, x1, acc0); acc1 = fmaf(d1, x1, acc1); acc2 = fmaf(d2, x1, acc2);
        acc3 = fmaf(d3, x1, acc3); acc4 = fmaf(d4, x1, acc4);
    }
    if (e < end) {
        int s0 = srcs[e];
        float x0 = hin[(size_t)s0 * 64 + lane];
        acc0 = fmaf(attr[e * 5 + 0], x0, acc0);
        acc1 = fmaf(attr[e * 5 + 1], x0, acc1);
        acc2 = fmaf(attr[e * 5 + 2], x0, acc2);
        acc3 = fmaf(attr[e * 5 + 3], x0, acc3);
        acc4 = fmaf(attr[e * 5 + 4], x0, acc4);
    }
    float* o = agg + (size_t)node * 320 + lane;
    o[0] = acc0; o[64] = acc1; o[128] = acc2; o[192] = acc3; o[256] = acc4;
}

// [64 nodes, 320] x [320, 64] + bias, relu. 256 threads, 4x4 register tile each.
__global__ __launch_bounds__(256) void k_transform(
    const float* __restrict__ A, const float* __restrict__ W,
    const float* __restrict__ bias, float* __restrict__ out) {
    int t = threadIdx.x;
    int tm = t >> 4, tn = t & 15;
    int n0 = blockIdx.x * 64 + tm * 4;
    int r[4];
#pragma unroll
    for (int j = 0; j < 4; ++j) { int rr = n0 + j; r[j] = rr < Nn ? rr : Nn - 1; }
    float acc[4][4];
#pragma unroll
    for (int j = 0; j < 4; ++j)
#pragma unroll
        for (int c = 0; c < 4; ++c) acc[j][c] = 0.f;
    const float* wp = W + tn * 4;
#pragma unroll 2
    for (int kk = 0; kk < 320; kk += 4) {
        float4 b0 = *(const float4*)(wp + (size_t)(kk + 0) * 64);
        float4 b1 = *(const float4*)(wp + (size_t)(kk + 1) * 64);
        float4 b2 = *(const float4*)(wp + (size_t)(kk + 2) * 64);
        float4 b3 = *(const float4*)(wp + (size_t)(kk + 3) * 64);
#pragma unroll
        for (int j = 0; j < 4; ++j) {
            float4 a = *(const float4*)(A + (size_t)r[j] * 320 + kk);
            acc[j][0] = fmaf(a.x, b0.x, fmaf(a.y, b1.x, fmaf(a.z, b2.x, fmaf(a.w, b3.x, acc[j][0]))));
            acc[j][1] = fmaf(a.x, b0.y, fmaf(a.y, b1.y, fmaf(a.z, b2.y, fmaf(a.w, b3.y, acc[j][1]))));
            acc[j][2] = fmaf(a.x, b0.z, fmaf(a.y, b1.z, fmaf(a.z, b2.z, fmaf(a.w, b3.z, acc[j][2]))));
            acc[j][3] = fmaf(a.x, b0.w, fmaf(a.y, b1.w, fmaf(a.z, b2.w, fmaf(a.w, b3.w, acc[j][3]))));
        }
    }
    float bb0 = bias[tn * 4 + 0], bb1 = bias[tn * 4 + 1];
    float bb2 = bias[tn * 4 + 2], bb3 = bias[tn * 4 + 3];
#pragma unroll
    for (int j = 0; j < 4; ++j) {
        int rr = n0 + j;
        if (rr < Nn) {
            float4 o;
            o.x = fmaxf(acc[j][0] + bb0, 0.f);
            o.y = fmaxf(acc[j][1] + bb1, 0.f);
            o.z = fmaxf(acc[j][2] + bb2, 0.f);
            o.w = fmaxf(acc[j][3] + bb3, 0.f);
            *(float4*)(out + (size_t)rr * 64 + tn * 4) = o;
        }
    }
}

// ---------------- pooling + head ----------------

__global__ __launch_bounds__(256) void k_pool(const float* __restrict__ h,
                                              const int* __restrict__ sg,
                                              const int* __restrict__ eg,
                                              float* __restrict__ pooled) {
    __shared__ float ls[256], lm[256];
    int g = blockIdx.x;
    int t = threadIdx.x, lane = t & 63, q = t >> 6;
    int s = sg[g], e = eg[g];
    float sum = 0.f, mx = 0.f;   // relu outputs are >= 0, so 0 is a valid max identity
    for (int n = s + q; n < e; n += 4) {
        float v = h[(size_t)n * 64 + lane];
        sum += v;
        mx = fmaxf(mx, v);
    }
    ls[t] = sum; lm[t] = mx;
    __syncthreads();
    if (q == 0) {
        float ss = ls[lane] + ls[64 + lane] + ls[128 + lane] + ls[192 + lane];
        float mm = fmaxf(fmaxf(lm[lane], lm[64 + lane]), fmaxf(lm[128 + lane], lm[192 + lane]));
        pooled[g * 128 + lane] = ss;
        pooled[g * 128 + 64 + lane] = mm;
    }
}

__global__ void k_head(const float* __restrict__ pooled, const float* __restrict__ gamma,
                       const float* __restrict__ beta, const float* __restrict__ mean,
                       const float* __restrict__ var, const float* __restrict__ fcw,
                       const float* __restrict__ fcb, float* __restrict__ out) {
    __shared__ float y[128];
    __shared__ float lg[8];
    int g = blockIdx.x, c = threadIdx.x;   // 128 threads
    float p = pooled[g * 128 + c];
    y[c] = (p - mean[c]) * rsqrtf(var[c] + 1e-5f) * gamma[c] + beta[c];
    __syncthreads();
    if (c < NCLSo) {
        float l = fcb[c];
        for (int i = 0; i < 128; ++i) l += y[i] * fcw[i * NCLSo + c];
        lg[c] = l;
    }
    __syncthreads();
    if (c == 0) {
        float m = lg[0];
        for (int j = 1; j < NCLSo; ++j) m = fmaxf(m, lg[j]);
        float se = 0.f;
        for (int j = 0; j < NCLSo; ++j) se += expf(lg[j] - m);
        float lse = m + logf(se);
        for (int j = 0; j < NCLSo; ++j) out[g * NCLSo + j] = lg[j] - lse;
    }
}

// ---------------- launch ----------------

static inline size_t rup(size_t x) { return (x + 255) & ~(size_t)255; }

extern "C" void kernel_launch(void* const* d_in, const int* in_sizes, int n_in,
                              void* d_out, int out_size, void* d_ws, size_t ws_size,
                              hipStream_t stream) {
    const float* x     = (const float*)d_in[0];
    const int*   ei    = (const int*)d_in[1];
    const float* eattr = (const float*)d_in[2];
    const int*   batch = (const int*)d_in[3];
    const float* W1    = (const float*)d_in[4];
    const float* b1    = (const float*)d_in[5];
    const float* W2    = (const float*)d_in[6];
    const float* b2    = (const float*)d_in[7];
    const float* W3    = (const float*)d_in[8];
    const float* b3    = (const float*)d_in[9];
    const float* W4    = (const float*)d_in[10];
    const float* b4    = (const float*)d_in[11];
    const float* gamma = (const float*)d_in[12];
    const float* beta  = (const float*)d_in[13];
    const float* mean  = (const float*)d_in[14];
    const float* var   = (const float*)d_in[15];
    const float* fcw   = (const float*)d_in[16];
    const float* fcb   = (const float*)d_in[17];
    float* out = (float*)d_out;

    char* p = (char*)d_ws;
    auto take = [&](size_t bytes) { char* r = p; p += rup(bytes); return r; };
    int*   deg      = (int*)take((size_t)(Nn + 1) * 4);
    int*   rowstart = (int*)take((size_t)(Nn + 1) * 4);
    int*   cursor   = (int*)take((size_t)(Nn + 1) * 4);
    int*   srcs     = (int*)take((size_t)Ne * 4);
    float* attr     = (float*)take((size_t)Ne * 5 * 4);
    float* hA       = (float*)take((size_t)Nn * 64 * 4);
    float* hB       = (float*)take((size_t)Nn * 64 * 4);
    float* agg      = (float*)take((size_t)Nn * 320 * 4);
    float* W1p      = (float*)take((size_t)NEk * 64 * 64 * 4);
    float* pooled   = (float*)take((size_t)Gg * 128 * 4);
    int*   sg       = (int*)take((size_t)Gg * 4);
    int*   eg       = (int*)take((size_t)Gg * 4);

    hipMemsetAsync(deg, 0, (size_t)(Nn + 1) * 4, stream);
    hipMemsetAsync(sg, 0x7f, (size_t)Gg * 4, stream);   // large positive ints
    hipMemsetAsync(eg, 0, (size_t)Gg * 4, stream);

    k_pad_x<<<(Nn * 64 + 255) / 256, 256, 0, stream>>>(x, hA);
    k_pad_w1<<<(NEk * 64 * 64 + 255) / 256, 256, 0, stream>>>(W1, W1p);
    k_hist<<<(Ne + 255) / 256, 256, 0, stream>>>(ei, deg);
    k_scan<<<1, 1024, 0, stream>>>(deg, rowstart, cursor);
    k_scatter<<<(Ne + 255) / 256, 256, 0, stream>>>(ei, eattr, cursor, srcs, attr);
    k_ranges<<<(Nn + 255) / 256, 256, 0, stream>>>(batch, sg, eg);

    const float* Ws[4] = { W1p, W2, W3, W4 };
    const float* bs[4] = { b1, b2, b3, b4 };
    float* cur = hA;
    float* nxt = hB;
    for (int L = 0; L < 4; ++L) {
        k_aggregate<<<Nn / 4, 256, 0, stream>>>(cur, rowstart, srcs, attr, agg);
        k_transform<<<(Nn + 63) / 64, 256, 0, stream>>>(agg, Ws[L], bs[L], nxt);
        float* tmp = cur; cur = nxt; nxt = tmp;
    }

    k_pool<<<Gg, 256, 0, stream>>>(cur, sg, eg, pooled);
    k_head<<<Gg, 128, 0, stream>>>(pooled, gamma, beta, mean, var, fcw, fcb, out);
}

// Round 2
// 1065.645 us; speedup vs baseline: 1.1777x; 1.1777x over previous
//
#include <hip/hip_runtime.h>

// GNNML3 forward: 4x SpectConv(K=5) + relu, sum/max pool per graph, BN + FC + log_softmax.
// Key identity: (S_k x) W_k == S_k (x W_k) -> aggregate at input width, then dense GEMM.
// CSR-by-dst built per call (histogram + multi-block scan + scatter) -> register accumulation.
// R2: k_ranges atomics -> sorted-boundary detection (batch is sorted by construction);
//     single-block scan -> 3-phase multi-block scan; edge attr SoA (float4+float, aligned).

#define Nn   50000
#define Ne   1600000
#define Gg   128
#define NEk  5
#define NINf 16
#define Hh   64
#define NCLSo 6
#define NB   196        // ceil((Nn+1)/256)

// ---------------- prep kernels ----------------

__global__ void k_pad_x(const float* __restrict__ x, float* __restrict__ h0) {
    int i = blockIdx.x * 256 + threadIdx.x;           // over Nn*64
    if (i >= Nn * 64) return;
    int n = i >> 6, f = i & 63;
    h0[i] = (f < NINf) ? x[n * NINf + f] : 0.f;
}

__global__ void k_pad_w1(const float* __restrict__ W1, float* __restrict__ W1p) {
    int i = blockIdx.x * 256 + threadIdx.x;           // over 5*64*64
    if (i >= NEk * 64 * 64) return;
    int h = i & 63, f = (i >> 6) & 63, k = i >> 12;
    W1p[i] = (f < NINf) ? W1[(k * NINf + f) * 64 + h] : 0.f;
}

__global__ void k_hist(const int* __restrict__ ei, int* __restrict__ deg) {
    int e = blockIdx.x * 256 + threadIdx.x;
    if (e >= Ne) return;
    atomicAdd(&deg[ei[Ne + e]], 1);                   // dst = ei[1][e]
}

// -------- 3-phase exclusive scan of deg[0..Nn] -> rowstart/cursor --------

__global__ void k_blocksum(const int* __restrict__ deg, int* __restrict__ bsum) {
    __shared__ int l[256];
    int t = threadIdx.x;
    int i = blockIdx.x * 256 + t;
    l[t] = (i < Nn) ? deg[i] : 0;
    __syncthreads();
    for (int off = 128; off > 0; off >>= 1) {
        if (t < off) l[t] += l[t + off];
        __syncthreads();
    }
    if (t == 0) bsum[blockIdx.x] = l[0];
}

__global__ void k_scanpart(const int* __restrict__ bsum, int* __restrict__ boff) {
    __shared__ int l[256];
    int t = threadIdx.x;
    int v = (t < NB) ? bsum[t] : 0;
    l[t] = v;
    __syncthreads();
    for (int off = 1; off < 256; off <<= 1) {
        int u = (t >= off) ? l[t - off] : 0;
        __syncthreads();
        l[t] += u;
        __syncthreads();
    }
    if (t < NB) boff[t] = l[t] - v;                   // exclusive
}

__global__ void k_scanfinal(const int* __restrict__ deg, const int* __restrict__ boff,
                            int* __restrict__ rowstart, int* __restrict__ cursor) {
    __shared__ int l[256];
    int t = threadIdx.x;
    int i = blockIdx.x * 256 + t;
    int v = (i < Nn) ? deg[i] : 0;
    l[t] = v;
    __syncthreads();
    for (int off = 1; off < 256; off <<= 1) {
        int u = (t >= off) ? l[t - off] : 0;
        __syncthreads();
        l[t] += u;
        __syncthreads();
    }
    if (i <= Nn) {
        int excl = boff[blockIdx.x] + l[t] - v;
        rowstart[i] = excl;
        cursor[i] = excl;
    }
}

__global__ void k_scatter(const int* __restrict__ ei, const float* __restrict__ eattr,
                          int* __restrict__ cursor, int* __restrict__ srcs,
                          float4* __restrict__ attr4, float* __restrict__ attr1) {
    int e = blockIdx.x * 256 + threadIdx.x;
    if (e >= Ne) return;
    int d = ei[Ne + e];
    int s = ei[e];
    int pos = atomicAdd(&cursor[d], 1);
    srcs[pos] = s;
    float a0 = eattr[e * 5 + 0], a1 = eattr[e * 5 + 1], a2 = eattr[e * 5 + 2];
    float a3 = eattr[e * 5 + 3], a4 = eattr[e * 5 + 4];
    attr4[pos] = make_float4(a0, a1, a2, a3);
    attr1[pos] = a4;
}

// batch is sorted (reference setup) -> segment bounds by boundary detection, no atomics
__global__ void k_bounds(const int* __restrict__ batch, int* __restrict__ sg,
                         int* __restrict__ eg) {
    int n = blockIdx.x * 256 + threadIdx.x;
    if (n >= Nn) return;
    int g = batch[n];
    if (n == 0) sg[g] = 0;
    else {
        int gp = batch[n - 1];
        if (gp != g) { sg[g] = n; eg[gp] = n; }
    }
    if (n == Nn - 1) eg[g] = Nn;
}

// ---------------- per-layer kernels ----------------

// one wave per node; lane = feature f (0..63); 5 register accumulators (spectral supports)
__global__ __launch_bounds__(256) void k_aggregate(
    const float* __restrict__ hin, const int* __restrict__ rowstart,
    const int* __restrict__ srcs, const float4* __restrict__ attr4,
    const float* __restrict__ attr1, float* __restrict__ agg) {
    int lane = threadIdx.x & 63;
    int node = __builtin_amdgcn_readfirstlane((int)(blockIdx.x * 4 + (threadIdx.x >> 6)));
    int beg = rowstart[node];
    int end = rowstart[node + 1];
    float acc0 = 0.f, acc1 = 0.f, acc2 = 0.f, acc3 = 0.f, acc4 = 0.f;
    int e = beg;
    for (; e + 2 <= end; e += 2) {
        int s0 = srcs[e], s1 = srcs[e + 1];
        float x0 = hin[(size_t)s0 * 64 + lane];
        float x1 = hin[(size_t)s1 * 64 + lane];
        float4 c = attr4[e];
        float4 d = attr4[e + 1];
        float c4 = attr1[e], d4 = attr1[e + 1];
        acc0 = fmaf(c.x, x0, acc0); acc1 = fmaf(c.y, x0, acc1); acc2 = fmaf(c.z, x0, acc2);
        acc3 = fmaf(c.w, x0, acc3); acc4 = fmaf(c4, x0, acc4);
        acc0 = fmaf(d.x, x1, acc0); acc1 = fmaf(d.y, x1, acc1); acc2 = fmaf(d.z, x1, acc2);
        acc3 = fmaf(d.w, x1, acc3); acc4 = fmaf(d4, x1, acc4);
    }
    if (e < end) {
        int s0 = srcs[e];
        float x0 = hin[(size_t)s0 * 64 + lane];
        float4 c = attr4[e];
        float c4 = attr1[e];
        acc0 = fmaf(c.x, x0, acc0); acc1 = fmaf(c.y, x0, acc1); acc2 = fmaf(c.z, x0, acc2);
        acc3 = fmaf(c.w, x0, acc3); acc4 = fmaf(c4, x0, acc4);
    }
    float* o = agg + (size_t)node * 320 + lane;
    o[0] = acc0; o[64] = acc1; o[128] = acc2; o[192] = acc3; o[256] = acc4;
}

// [64 nodes, 320] x [320, 64] + bias, relu. 256 threads, 4x4 register tile each.
__global__ __launch_bounds__(256) void k_transform(
    const float* __restrict__ A, const float* __restrict__ W,
    const float* __restrict__ bias, float* __restrict__ out) {
    int t = threadIdx.x;
    int tm = t >> 4, tn = t & 15;
    int n0 = blockIdx.x * 64 + tm * 4;
    int r[4];
#pragma unroll
    for (int j = 0; j < 4; ++j) { int rr = n0 + j; r[j] = rr < Nn ? rr : Nn - 1; }
    float acc[4][4];
#pragma unroll
    for (int j = 0; j < 4; ++j)
#pragma unroll
        for (int c = 0; c < 4; ++c) acc[j][c] = 0.f;
    const float* wp = W + tn * 4;
#pragma unroll 2
    for (int kk = 0; kk < 320; kk += 4) {
        float4 b0 = *(const float4*)(wp + (size_t)(kk + 0) * 64);
        float4 b1 = *(const float4*)(wp + (size_t)(kk + 1) * 64);
        float4 b2 = *(const float4*)(wp + (size_t)(kk + 2) * 64);
        float4 b3 = *(const float4*)(wp + (size_t)(kk + 3) * 64);
#pragma unroll
        for (int j = 0; j < 4; ++j) {
            float4 a = *(const float4*)(A + (size_t)r[j] * 320 + kk);
            acc[j][0] = fmaf(a.x, b0.x, fmaf(a.y, b1.x, fmaf(a.z, b2.x, fmaf(a.w, b3.x, acc[j][0]))));
            acc[j][1] = fmaf(a.x, b0.y, fmaf(a.y, b1.y, fmaf(a.z, b2.y, fmaf(a.w, b3.y, acc[j][1]))));
            acc[j][2] = fmaf(a.x, b0.z, fmaf(a.y, b1.z, fmaf(a.z, b2.z, fmaf(a.w, b3.z, acc[j][2]))));
            acc[j][3] = fmaf(a.x, b0.w, fmaf(a.y, b1.w, fmaf(a.z, b2.w, fmaf(a.w, b3.w, acc[j][3]))));
        }
    }
    float bb0 = bias[tn * 4 + 0], bb1 = bias[tn * 4 + 1];
    float bb2 = bias[tn * 4 + 2], bb3 = bias[tn * 4 + 3];
#pragma unroll
    for (int j = 0; j < 4; ++j) {
        int rr = n0 + j;
        if (rr < Nn) {
            float4 o;
            o.x = fmaxf(acc[j][0] + bb0, 0.f);
            o.y = fmaxf(acc[j][1] + bb1, 0.f);
            o.z = fmaxf(acc[j][2] + bb2, 0.f);
            o.w = fmaxf(acc[j][3] + bb3, 0.f);
            *(float4*)(out + (size_t)rr * 64 + tn * 4) = o;
        }
    }
}

// ---------------- pooling + head ----------------

__global__ __launch_bounds__(256) void k_pool(const float* __restrict__ h,
                                              const int* __restrict__ sg,
                                              const int* __restrict__ eg,
                                              float* __restrict__ pooled) {
    __shared__ float ls[256], lm[256];
    int g = blockIdx.x;
    int t = threadIdx.x, lane = t & 63, q = t >> 6;
    int s = sg[g], e = eg[g];
    float sum = 0.f, mx = 0.f;   // relu outputs are >= 0, so 0 is a valid max identity
    for (int n = s + q; n < e; n += 4) {
        float v = h[(size_t)n * 64 + lane];
        sum += v;
        mx = fmaxf(mx, v);
    }
    ls[t] = sum; lm[t] = mx;
    __syncthreads();
    if (q == 0) {
        float ss = ls[lane] + ls[64 + lane] + ls[128 + lane] + ls[192 + lane];
        float mm = fmaxf(fmaxf(lm[lane], lm[64 + lane]), fmaxf(lm[128 + lane], lm[192 + lane]));
        pooled[g * 128 + lane] = ss;
        pooled[g * 128 + 64 + lane] = mm;
    }
}

__global__ void k_head(const float* __restrict__ pooled, const float* __restrict__ gamma,
                       const float* __restrict__ beta, const float* __restrict__ mean,
                       const float* __restrict__ var, const float* __restrict__ fcw,
                       const float* __restrict__ fcb, float* __restrict__ out) {
    __shared__ float y[128];
    __shared__ float lg[8];
    int g = blockIdx.x, c = threadIdx.x;   // 128 threads
    float p = pooled[g * 128 + c];
    y[c] = (p - mean[c]) * rsqrtf(var[c] + 1e-5f) * gamma[c] + beta[c];
    __syncthreads();
    if (c < NCLSo) {
        float l = fcb[c];
        for (int i = 0; i < 128; ++i) l += y[i] * fcw[i * NCLSo + c];
        lg[c] = l;
    }
    __syncthreads();
    if (c == 0) {
        float m = lg[0];
        for (int j = 1; j < NCLSo; ++j) m = fmaxf(m, lg[j]);
        float se = 0.f;
        for (int j = 0; j < NCLSo; ++j) se += expf(lg[j] - m);
        float lse = m + logf(se);
        for (int j = 0; j < NCLSo; ++j) out[g * NCLSo + j] = lg[j] - lse;
    }
}

// ---------------- launch ----------------

static inline size_t rup(size_t x) { return (x + 255) & ~(size_t)255; }

extern "C" void kernel_launch(void* const* d_in, const int* in_sizes, int n_in,
                              void* d_out, int out_size, void* d_ws, size_t ws_size,
                              hipStream_t stream) {
    const float* x     = (const float*)d_in[0];
    const int*   ei    = (const int*)d_in[1];
    const float* eattr = (const float*)d_in[2];
    const int*   batch = (const int*)d_in[3];
    const float* W1    = (const float*)d_in[4];
    const float* b1    = (const float*)d_in[5];
    const float* W2    = (const float*)d_in[6];
    const float* b2    = (const float*)d_in[7];
    const float* W3    = (const float*)d_in[8];
    const float* b3    = (const float*)d_in[9];
    const float* W4    = (const float*)d_in[10];
    const float* b4    = (const float*)d_in[11];
    const float* gamma = (const float*)d_in[12];
    const float* beta  = (const float*)d_in[13];
    const float* mean  = (const float*)d_in[14];
    const float* var   = (const float*)d_in[15];
    const float* fcw   = (const float*)d_in[16];
    const float* fcb   = (const float*)d_in[17];
    float* out = (float*)d_out;

    char* p = (char*)d_ws;
    auto take = [&](size_t bytes) { char* r = p; p += rup(bytes); return r; };
    int*    deg      = (int*)take((size_t)(Nn + 1) * 4);
    int*    rowstart = (int*)take((size_t)(Nn + 1) * 4);
    int*    cursor   = (int*)take((size_t)(Nn + 1) * 4);
    int*    bsum     = (int*)take((size_t)NB * 4);
    int*    boff     = (int*)take((size_t)NB * 4);
    int*    srcs     = (int*)take((size_t)Ne * 4);
    float4* attr4    = (float4*)take((size_t)Ne * 16);
    float*  attr1    = (float*)take((size_t)Ne * 4);
    float*  hA       = (float*)take((size_t)Nn * 64 * 4);
    float*  hB       = (float*)take((size_t)Nn * 64 * 4);
    float*  agg      = (float*)take((size_t)Nn * 320 * 4);
    float*  W1p      = (float*)take((size_t)NEk * 64 * 64 * 4);
    float*  pooled   = (float*)take((size_t)Gg * 128 * 4);
    int*    sg       = (int*)take((size_t)Gg * 4);
    int*    eg       = (int*)take((size_t)Gg * 4);

    hipMemsetAsync(deg, 0, (size_t)(Nn + 1) * 4, stream);

    k_pad_x<<<(Nn * 64 + 255) / 256, 256, 0, stream>>>(x, hA);
    k_pad_w1<<<(NEk * 64 * 64 + 255) / 256, 256, 0, stream>>>(W1, W1p);
    k_hist<<<(Ne + 255) / 256, 256, 0, stream>>>(ei, deg);
    k_blocksum<<<NB, 256, 0, stream>>>(deg, bsum);
    k_scanpart<<<1, 256, 0, stream>>>(bsum, boff);
    k_scanfinal<<<NB, 256, 0, stream>>>(deg, boff, rowstart, cursor);
    k_scatter<<<(Ne + 255) / 256, 256, 0, stream>>>(ei, eattr, cursor, srcs, attr4, attr1);
    k_bounds<<<(Nn + 255) / 256, 256, 0, stream>>>(batch, sg, eg);

    const float* Ws[4] = { W1p, W2, W3, W4 };
    const float* bs[4] = { b1, b2, b3, b4 };
    float* cur = hA;
    float* nxt = hB;
    for (int L = 0; L < 4; ++L) {
        k_aggregate<<<Nn / 4, 256, 0, stream>>>(cur, rowstart, srcs, attr4, attr1, agg);
        k_transform<<<(Nn + 63) / 64, 256, 0, stream>>>(agg, Ws[L], bs[L], nxt);
        float* tmp = cur; cur = nxt; nxt = tmp;
    }

    k_pool<<<Gg, 256, 0, stream>>>(cur, sg, eg, pooled);
    k_head<<<Gg, 128, 0, stream>>>(pooled, gamma, beta, mean, var, fcw, fcb, out);
}